// Round 6
// baseline (536.479 us; speedup 1.0000x reference)
//
#include <hip/hip_runtime.h>

// ---------------------------------------------------------------------------
// GCN forward, CSR-based. N=100000 nodes, E=1600000 edges.
//   build CSR by destination (once):  cnt -> scan -> XCD-partitioned scatter
//   per layer:  H = (relu?)(X) @ W * dinv[row]        (gemm_tile_kernel)
//               X[c] = b + dinv[c]*(sum_{r in N(c)} H[r] + H[c])   (agg_csr)
// ---------------------------------------------------------------------------

__device__ inline void f4acc(float4& a, const float4 v) {
    a.x += v.x; a.y += v.y; a.z += v.z; a.w += v.w;
}

__global__ __launch_bounds__(256) void zero_i32_kernel(int* __restrict__ p, int n) {
    int i = blockIdx.x * blockDim.x + threadIdx.x;
    if (i < n) p[i] = 0;
}

__global__ __launch_bounds__(256) void hist_kernel(const int* __restrict__ col,
                                                   int* __restrict__ cnt, int E) {
    int e = blockIdx.x * blockDim.x + threadIdx.x;
    if (e < E) atomicAdd(&cnt[col[e]], 1);
}

__global__ __launch_bounds__(256) void dinv_kernel(const int* __restrict__ cnt,
                                                   float* __restrict__ dinv, int N) {
    int i = blockIdx.x * blockDim.x + threadIdx.x;
    if (i < N) dinv[i] = rsqrtf((float)cnt[i] + 1.0f);  // +1 self-loop
}

__global__ __launch_bounds__(256) void block_reduce_kernel(const int* __restrict__ cnt,
                                                           int* __restrict__ bsum, int N) {
    __shared__ int s[256];
    int i = blockIdx.x * 256 + threadIdx.x;
    s[threadIdx.x] = (i < N) ? cnt[i] : 0;
    __syncthreads();
    for (int off = 128; off > 0; off >>= 1) {
        if (threadIdx.x < off) s[threadIdx.x] += s[threadIdx.x + off];
        __syncthreads();
    }
    if (threadIdx.x == 0) bsum[blockIdx.x] = s[0];
}

// single block of 512 threads, exclusive-scans bsum in place (nb <= 512)
__global__ __launch_bounds__(512) void scan_bsums_kernel(int* __restrict__ bsum, int nb) {
    __shared__ int s[512];
    int tid = threadIdx.x;
    int v = (tid < nb) ? bsum[tid] : 0;
    s[tid] = v;
    __syncthreads();
    for (int off = 1; off < 512; off <<= 1) {
        int t = (tid >= off) ? s[tid - off] : 0;
        __syncthreads();
        s[tid] += t;
        __syncthreads();
    }
    if (tid < nb) bsum[tid] = s[tid] - v;  // exclusive
}

__global__ __launch_bounds__(256) void scan_kernel(const int* __restrict__ cnt,
                                                   const int* __restrict__ bsum,
                                                   int* __restrict__ offs, int N) {
    __shared__ int s[256];
    int i = blockIdx.x * 256 + threadIdx.x;
    int v = (i < N) ? cnt[i] : 0;
    s[threadIdx.x] = v;
    __syncthreads();
    for (int off = 1; off < 256; off <<= 1) {
        int t = (threadIdx.x >= off) ? s[threadIdx.x - off] : 0;
        __syncthreads();
        s[threadIdx.x] += t;
        __syncthreads();
    }
    int excl = s[threadIdx.x] - v + bsum[blockIdx.x];
    if (i < N) offs[i] = excl;
    if (i == N - 1) offs[N] = excl + v;
}

__global__ __launch_bounds__(256) void copy_i32_kernel(const int* __restrict__ src,
                                                       int* __restrict__ dst, int n) {
    int i = blockIdx.x * blockDim.x + threadIdx.x;
    if (i < n) dst[i] = src[i];
}

// XCD-partitioned scatter: blocks with (blockIdx & 7) == p handle only edges
// whose destination lies in partition p's node range (kills cross-XCD line
// thrash on eidx writes; see round-3 -> round-4 WRITE_SIZE drop).
__global__ __launch_bounds__(256) void scatter_part_kernel(const int* __restrict__ row,
                                                           const int* __restrict__ col,
                                                           int* __restrict__ cursor,
                                                           int* __restrict__ eidx,
                                                           int E, int span) {
    const int part = blockIdx.x & 7;
    const int lo = part * span, hi = lo + span;
    const int nwg = gridDim.x >> 3;
    const int wg  = blockIdx.x >> 3;
    for (int e = wg * 256 + threadIdx.x; e < E; e += nwg * 256) {
        int c = col[e];
        if (c >= lo && c < hi) {
            int pos = atomicAdd(&cursor[c], 1);
            eidx[pos] = row[e];
        }
    }
}

// H = ((RELU? relu(in) : in) @ W) * dinv[row].   W is [F_IN, F_OUT] row-major.
// __launch_bounds__(256,4): cap VGPR at 128 (round-4: 248 VGPR / 9.6% occ was
// latency-bound). Inner unroll capped at 2 to avoid scratch spills.
template <int F_IN, int F_OUT, bool RELU>
__global__ __launch_bounds__(256, 4) void gemm_tile_kernel(const float* __restrict__ in,
                                                           const float* __restrict__ W,
                                                           const float* __restrict__ dinv,
                                                           float* __restrict__ out, int N) {
    constexpr int TC   = F_OUT / 4;   // col-thread groups (16 or 8)
    constexpr int TR   = 256 / TC;    // row-thread groups (16 or 32)
    constexpr int ROWS = TR * 4;      // rows per block (64 or 128)
    constexpr int NKB  = F_IN / 64;   // k-blocks of 64
    __shared__ float sIn[ROWS][68];
    __shared__ float sW[64][F_OUT];

    const int tc = threadIdx.x % TC;
    const int tr = threadIdx.x / TC;
    const int r0 = blockIdx.x * ROWS;

    float acc[4][4] = {};

#pragma unroll
    for (int kb = 0; kb < NKB; ++kb) {
        if (kb) __syncthreads();
        for (int idx = threadIdx.x; idx < ROWS * 16; idx += 256) {
            int rr = idx / 16, c4 = (idx % 16) * 4;
            int gr = min(r0 + rr, N - 1);
            float4 v = *(const float4*)&in[(size_t)gr * F_IN + kb * 64 + c4];
            if (RELU) {
                v.x = fmaxf(v.x, 0.f); v.y = fmaxf(v.y, 0.f);
                v.z = fmaxf(v.z, 0.f); v.w = fmaxf(v.w, 0.f);
            }
            *(float4*)&sIn[rr][c4] = v;
        }
        for (int idx = threadIdx.x; idx < 64 * F_OUT / 4; idx += 256) {
            int kr = idx / (F_OUT / 4), c4 = (idx % (F_OUT / 4)) * 4;
            *(float4*)&sW[kr][c4] = *(const float4*)&W[(size_t)(kb * 64 + kr) * F_OUT + c4];
        }
        __syncthreads();
#pragma unroll 2
        for (int kk = 0; kk < 64; kk += 4) {
            float4 iv[4], wv[4];
#pragma unroll
            for (int i = 0; i < 4; ++i) iv[i] = *(const float4*)&sIn[tr * 4 + i][kk];
#pragma unroll
            for (int q = 0; q < 4; ++q) wv[q] = *(const float4*)&sW[kk + q][tc * 4];
#pragma unroll
            for (int i = 0; i < 4; ++i) {
                const float ik[4] = {iv[i].x, iv[i].y, iv[i].z, iv[i].w};
#pragma unroll
                for (int q = 0; q < 4; ++q) {
                    acc[i][0] = fmaf(ik[q], wv[q].x, acc[i][0]);
                    acc[i][1] = fmaf(ik[q], wv[q].y, acc[i][1]);
                    acc[i][2] = fmaf(ik[q], wv[q].z, acc[i][2]);
                    acc[i][3] = fmaf(ik[q], wv[q].w, acc[i][3]);
                }
            }
        }
    }
#pragma unroll
    for (int i = 0; i < 4; ++i) {
        int r = r0 + tr * 4 + i;
        if (r < N) {
            float d = dinv[r];
            float4 v = {acc[i][0] * d, acc[i][1] * d, acc[i][2] * d, acc[i][3] * d};
            *(float4*)&out[(size_t)r * F_OUT + tc * 4] = v;
        }
    }
}

// out[c, j4..j4+3] = b + dinv[c] * ( sum_{neighbors} H[r] + H[c] ), float4 lanes.
// 8-deep unroll: 8 independent eidx loads then 8 independent dwordx4 gathers
// in flight per lane (round-5 profile: F=32 agg == F=64 agg duration at half
// the bytes -> latency-bound, not BW-bound; deepen MLP).
template <int F>
__global__ __launch_bounds__(256) void agg_csr_kernel(const float* __restrict__ h,
                                                      const int* __restrict__ offs,
                                                      const int* __restrict__ eidx,
                                                      const float* __restrict__ dinv,
                                                      const float* __restrict__ b,
                                                      float* __restrict__ out, int N) {
    constexpr int L = F / 4;  // lanes per node (16 or 8)
    int seg = (blockIdx.x * 256 + threadIdx.x) / L;
    int j4  = (threadIdx.x % L) * 4;
    if (seg >= N) return;
    int s = offs[seg];
    int e = offs[seg + 1];

    float4 a0 = {0.f, 0.f, 0.f, 0.f}, a1 = a0, a2 = a0, a3 = a0;
    float4 a4 = a0, a5 = a0, a6 = a0, a7 = a0;
    int k = s;
    for (; k + 8 <= e; k += 8) {
        int r0 = eidx[k],     r1 = eidx[k + 1], r2 = eidx[k + 2], r3 = eidx[k + 3];
        int r4 = eidx[k + 4], r5 = eidx[k + 5], r6 = eidx[k + 6], r7 = eidx[k + 7];
        f4acc(a0, *(const float4*)&h[(size_t)r0 * F + j4]);
        f4acc(a1, *(const float4*)&h[(size_t)r1 * F + j4]);
        f4acc(a2, *(const float4*)&h[(size_t)r2 * F + j4]);
        f4acc(a3, *(const float4*)&h[(size_t)r3 * F + j4]);
        f4acc(a4, *(const float4*)&h[(size_t)r4 * F + j4]);
        f4acc(a5, *(const float4*)&h[(size_t)r5 * F + j4]);
        f4acc(a6, *(const float4*)&h[(size_t)r6 * F + j4]);
        f4acc(a7, *(const float4*)&h[(size_t)r7 * F + j4]);
    }
    if (k + 4 <= e) {
        int r0 = eidx[k], r1 = eidx[k + 1], r2 = eidx[k + 2], r3 = eidx[k + 3];
        f4acc(a0, *(const float4*)&h[(size_t)r0 * F + j4]);
        f4acc(a1, *(const float4*)&h[(size_t)r1 * F + j4]);
        f4acc(a2, *(const float4*)&h[(size_t)r2 * F + j4]);
        f4acc(a3, *(const float4*)&h[(size_t)r3 * F + j4]);
        k += 4;
    }
    for (; k < e; ++k) f4acc(a0, *(const float4*)&h[(size_t)eidx[k] * F + j4]);

    f4acc(a0, a4); f4acc(a1, a5); f4acc(a2, a6); f4acc(a3, a7);
    f4acc(a0, a1); f4acc(a2, a3); f4acc(a0, a2);
    f4acc(a0, *(const float4*)&h[(size_t)seg * F + j4]);  // self-loop
    float4 bv = *(const float4*)&b[j4];
    float  d  = dinv[seg];
    float4 o  = {bv.x + d * a0.x, bv.y + d * a0.y, bv.z + d * a0.z, bv.w + d * a0.w};
    *(float4*)&out[(size_t)seg * F + j4] = o;
}

extern "C" void kernel_launch(void* const* d_in, const int* in_sizes, int n_in,
                              void* d_out, int out_size, void* d_ws, size_t ws_size,
                              hipStream_t stream) {
    const float* x  = (const float*)d_in[0];
    const int*   ei = (const int*)d_in[1];
    const float* W1 = (const float*)d_in[2];
    const float* b1 = (const float*)d_in[3];
    const float* W2 = (const float*)d_in[4];
    const float* b2 = (const float*)d_in[5];
    const float* W3 = (const float*)d_in[6];
    const float* b3 = (const float*)d_in[7];
    const float* W4 = (const float*)d_in[8];
    const float* b4 = (const float*)d_in[9];

    const int N = in_sizes[0] / 128;  // 100000
    const int E = in_sizes[1] / 2;    // 1600000
    const int* row = ei;              // source
    const int* col = ei + E;          // destination

    // ---- workspace layout ---------------------------------------------------
    char* w = (char*)d_ws;
    int*   cnt    = (int*)w;                 w += (size_t)N * 4;
    int*   offs   = (int*)w;                 w += (size_t)(N + 1) * 4;
    int*   cursor = (int*)w;                 w += (size_t)N * 4;
    int*   bsum   = (int*)w;                 w += 512 * 4;
    float* dinv   = (float*)w;               w += (size_t)N * 4;
    int*   eidx   = (int*)w;                 w += (size_t)E * 4;
    float* X      = (float*)w;               w += (size_t)N * 64 * 4;
    float* H      = (float*)w;
    float* out    = (float*)d_out;

    const int T  = 256;
    const int NB = (N + T - 1) / T;  // 391

    // ---- CSR build + norm ---------------------------------------------------
    zero_i32_kernel<<<NB, T, 0, stream>>>(cnt, N);
    hist_kernel<<<(E + T - 1) / T, T, 0, stream>>>(col, cnt, E);
    dinv_kernel<<<NB, T, 0, stream>>>(cnt, dinv, N);
    block_reduce_kernel<<<NB, T, 0, stream>>>(cnt, bsum, N);
    scan_bsums_kernel<<<1, 512, 0, stream>>>(bsum, NB);
    scan_kernel<<<NB, T, 0, stream>>>(cnt, bsum, offs, N);
    copy_i32_kernel<<<NB, T, 0, stream>>>(offs, cursor, N);
    scatter_part_kernel<<<2048, T, 0, stream>>>(row, col, cursor, eidx, E, (N + 7) / 8);

    const int g64 = (N + 63) / 64;    // gemm blocks, 64 rows/block (F_OUT=64)
    const int g32 = (N + 127) / 128;  // gemm blocks, 128 rows/block (F_OUT=32)
    const int a64 = (N * 16 + T - 1) / T;  // agg blocks, 16 lanes/node
    const int a32 = (N * 8 + T - 1) / T;   // agg blocks, 8 lanes/node

    // ---- layer 1: x[128] -> 64 ---------------------------------------------
    gemm_tile_kernel<128, 64, false><<<g64, T, 0, stream>>>(x, W1, dinv, H, N);
    agg_csr_kernel<64><<<a64, T, 0, stream>>>(H, offs, eidx, dinv, b1, X, N);
    // ---- layer 2 ------------------------------------------------------------
    gemm_tile_kernel<64, 64, true><<<g64, T, 0, stream>>>(X, W2, dinv, H, N);
    agg_csr_kernel<64><<<a64, T, 0, stream>>>(H, offs, eidx, dinv, b2, X, N);
    // ---- layer 3 ------------------------------------------------------------
    gemm_tile_kernel<64, 64, true><<<g64, T, 0, stream>>>(X, W3, dinv, H, N);
    agg_csr_kernel<64><<<a64, T, 0, stream>>>(H, offs, eidx, dinv, b3, X, N);
    // ---- layer 4: 64 -> 32, no ReLU, straight to d_out ----------------------
    gemm_tile_kernel<64, 32, true><<<g32, T, 0, stream>>>(X, W4, dinv, H, N);
    agg_csr_kernel<32><<<a32, T, 0, stream>>>(H, offs, eidx, dinv, b4, out, N);
}

// Round 7
// 529.296 us; speedup vs baseline: 1.0136x; 1.0136x over previous
//
#include <hip/hip_runtime.h>

// ---------------------------------------------------------------------------
// GCN forward, source-bucketed-CSR. N=100000 nodes, E=1600000 edges.
//   CSR by destination with neighbor lists bucketed by source range (8 buckets
//   of ceil(N/8) nodes = 3.2 MB of H each -> every XCD L2 can cache a slice).
//   per layer:  H = (relu?)(X) @ W * dinv[row]            (gemm_tile_kernel)
//               X[c] = b + dinv[c]*(sum_q sum_{r in bucket q} H[r] + H[c])
//                 (agg walks buckets in lockstep phases -> L2-resident gathers)
// ---------------------------------------------------------------------------

#define NBKT 8

__device__ inline void f4acc(float4& a, const float4 v) {
    a.x += v.x; a.y += v.y; a.z += v.z; a.w += v.w;
}

__global__ __launch_bounds__(256) void zero_i32_kernel(int* __restrict__ p, int n) {
    int i = blockIdx.x * blockDim.x + threadIdx.x;
    if (i < n) p[i] = 0;
}

// cnt2[c*8 + src/span] ++
__global__ __launch_bounds__(256) void hist2_kernel(const int* __restrict__ row,
                                                    const int* __restrict__ col,
                                                    int* __restrict__ cnt2, int E, int span) {
    int e = blockIdx.x * blockDim.x + threadIdx.x;
    if (e < E) {
        int c = col[e], r = row[e];
        atomicAdd(&cnt2[(size_t)c * NBKT + r / span], 1);
    }
}

__global__ __launch_bounds__(256) void dinv2_kernel(const int* __restrict__ offs2,
                                                    float* __restrict__ dinv, int N) {
    int i = blockIdx.x * blockDim.x + threadIdx.x;
    if (i < N) {
        int deg = offs2[i * NBKT + NBKT] - offs2[i * NBKT];
        dinv[i] = rsqrtf((float)deg + 1.0f);  // +1 self-loop
    }
}

__global__ __launch_bounds__(256) void block_reduce_kernel(const int* __restrict__ cnt,
                                                           int* __restrict__ bsum, int n) {
    __shared__ int s[256];
    int i = blockIdx.x * 256 + threadIdx.x;
    s[threadIdx.x] = (i < n) ? cnt[i] : 0;
    __syncthreads();
    for (int off = 128; off > 0; off >>= 1) {
        if (threadIdx.x < off) s[threadIdx.x] += s[threadIdx.x + off];
        __syncthreads();
    }
    if (threadIdx.x == 0) bsum[blockIdx.x] = s[0];
}

// single block, exclusive-scans bsum[nb] in place, any nb (chunks of 512)
__global__ __launch_bounds__(512) void scan_bsums_big_kernel(int* __restrict__ bsum, int nb) {
    __shared__ int s[512];
    int tid = threadIdx.x;
    int run = 0;
    for (int start = 0; start < nb; start += 512) {
        int i = start + tid;
        int v = (i < nb) ? bsum[i] : 0;
        s[tid] = v;
        __syncthreads();
        for (int off = 1; off < 512; off <<= 1) {
            int t = (tid >= off) ? s[tid - off] : 0;
            __syncthreads();
            s[tid] += t;
            __syncthreads();
        }
        if (i < nb) bsum[i] = s[tid] - v + run;  // exclusive + carry
        int tot = s[511];
        __syncthreads();
        run += tot;
    }
}

__global__ __launch_bounds__(256) void scan_kernel(const int* __restrict__ cnt,
                                                   const int* __restrict__ bsum,
                                                   int* __restrict__ offs, int n) {
    __shared__ int s[256];
    int i = blockIdx.x * 256 + threadIdx.x;
    int v = (i < n) ? cnt[i] : 0;
    s[threadIdx.x] = v;
    __syncthreads();
    for (int off = 1; off < 256; off <<= 1) {
        int t = (threadIdx.x >= off) ? s[threadIdx.x - off] : 0;
        __syncthreads();
        s[threadIdx.x] += t;
        __syncthreads();
    }
    int excl = s[threadIdx.x] - v + bsum[blockIdx.x];
    if (i < n) offs[i] = excl;
    if (i == n - 1) offs[n] = excl + v;
}

__global__ __launch_bounds__(256) void copy_i32_kernel(const int* __restrict__ src,
                                                       int* __restrict__ dst, int n) {
    int i = blockIdx.x * blockDim.x + threadIdx.x;
    if (i < n) dst[i] = src[i];
}

// XCD-partitioned by dest range (write locality on eidx/cursor); bucket slot
// chosen by source range.
__global__ __launch_bounds__(256) void scatter2_kernel(const int* __restrict__ row,
                                                       const int* __restrict__ col,
                                                       int* __restrict__ cursor,
                                                       int* __restrict__ eidx,
                                                       int E, int span) {
    const int part = blockIdx.x & 7;
    const int lo = part * span, hi = lo + span;
    const int nwg = gridDim.x >> 3;
    const int wg  = blockIdx.x >> 3;
    for (int e = wg * 256 + threadIdx.x; e < E; e += nwg * 256) {
        int c = col[e];
        if (c >= lo && c < hi) {
            int r = row[e];
            int pos = atomicAdd(&cursor[(size_t)c * NBKT + r / span], 1);
            eidx[pos] = r;
        }
    }
}

// H = ((RELU? relu(in) : in) @ W) * dinv[row].   W is [F_IN, F_OUT] row-major.
// __launch_bounds__(256,4): cap VGPR at 128 (round-4: 248 VGPR / 9.6% occ was
// latency-bound). Inner unroll capped at 2 to avoid scratch spills.
template <int F_IN, int F_OUT, bool RELU>
__global__ __launch_bounds__(256, 4) void gemm_tile_kernel(const float* __restrict__ in,
                                                           const float* __restrict__ W,
                                                           const float* __restrict__ dinv,
                                                           float* __restrict__ out, int N) {
    constexpr int TC   = F_OUT / 4;   // col-thread groups (16 or 8)
    constexpr int TR   = 256 / TC;    // row-thread groups (16 or 32)
    constexpr int ROWS = TR * 4;      // rows per block (64 or 128)
    constexpr int NKB  = F_IN / 64;   // k-blocks of 64
    __shared__ float sIn[ROWS][68];
    __shared__ float sW[64][F_OUT];

    const int tc = threadIdx.x % TC;
    const int tr = threadIdx.x / TC;
    const int r0 = blockIdx.x * ROWS;

    float acc[4][4] = {};

#pragma unroll
    for (int kb = 0; kb < NKB; ++kb) {
        if (kb) __syncthreads();
        for (int idx = threadIdx.x; idx < ROWS * 16; idx += 256) {
            int rr = idx / 16, c4 = (idx % 16) * 4;
            int gr = min(r0 + rr, N - 1);
            float4 v = *(const float4*)&in[(size_t)gr * F_IN + kb * 64 + c4];
            if (RELU) {
                v.x = fmaxf(v.x, 0.f); v.y = fmaxf(v.y, 0.f);
                v.z = fmaxf(v.z, 0.f); v.w = fmaxf(v.w, 0.f);
            }
            *(float4*)&sIn[rr][c4] = v;
        }
        for (int idx = threadIdx.x; idx < 64 * F_OUT / 4; idx += 256) {
            int kr = idx / (F_OUT / 4), c4 = (idx % (F_OUT / 4)) * 4;
            *(float4*)&sW[kr][c4] = *(const float4*)&W[(size_t)(kb * 64 + kr) * F_OUT + c4];
        }
        __syncthreads();
#pragma unroll 2
        for (int kk = 0; kk < 64; kk += 4) {
            float4 iv[4], wv[4];
#pragma unroll
            for (int i = 0; i < 4; ++i) iv[i] = *(const float4*)&sIn[tr * 4 + i][kk];
#pragma unroll
            for (int q = 0; q < 4; ++q) wv[q] = *(const float4*)&sW[kk + q][tc * 4];
#pragma unroll
            for (int i = 0; i < 4; ++i) {
                const float ik[4] = {iv[i].x, iv[i].y, iv[i].z, iv[i].w};
#pragma unroll
                for (int q = 0; q < 4; ++q) {
                    acc[i][0] = fmaf(ik[q], wv[q].x, acc[i][0]);
                    acc[i][1] = fmaf(ik[q], wv[q].y, acc[i][1]);
                    acc[i][2] = fmaf(ik[q], wv[q].z, acc[i][2]);
                    acc[i][3] = fmaf(ik[q], wv[q].w, acc[i][3]);
                }
            }
        }
    }
#pragma unroll
    for (int i = 0; i < 4; ++i) {
        int r = r0 + tr * 4 + i;
        if (r < N) {
            float d = dinv[r];
            float4 v = {acc[i][0] * d, acc[i][1] * d, acc[i][2] * d, acc[i][3] * d};
            *(float4*)&out[(size_t)r * F_OUT + tc * 4] = v;
        }
    }
}

// Phase-ordered aggregation: outer loop over 8 source buckets; at phase q all
// concurrent waves gather from the same 3.2 MB slice of h -> L2-resident.
// offs2 is [N*8+1]; dest c's bucket q spans [offs2[c*8+q], offs2[c*8+q+1]).
template <int F>
__global__ __launch_bounds__(256) void agg_csr_kernel(const float* __restrict__ h,
                                                      const int* __restrict__ offs2,
                                                      const int* __restrict__ eidx,
                                                      const float* __restrict__ dinv,
                                                      const float* __restrict__ b,
                                                      float* __restrict__ out, int N) {
    constexpr int L = F / 4;  // lanes per node (16 or 8)
    int seg = (blockIdx.x * 256 + threadIdx.x) / L;
    int j4  = (threadIdx.x % L) * 4;
    if (seg >= N) return;

    const int base = seg * NBKT;
    float4 a0 = {0.f, 0.f, 0.f, 0.f}, a1 = a0;
    int ks = offs2[base];
#pragma unroll
    for (int q = 0; q < NBKT; ++q) {
        int ke = offs2[base + q + 1];
        int k = ks;
        for (; k + 2 <= ke; k += 2) {
            int r0 = eidx[k], r1 = eidx[k + 1];
            f4acc(a0, *(const float4*)&h[(size_t)r0 * F + j4]);
            f4acc(a1, *(const float4*)&h[(size_t)r1 * F + j4]);
        }
        if (k < ke) f4acc(a0, *(const float4*)&h[(size_t)eidx[k] * F + j4]);
        ks = ke;
    }

    f4acc(a0, a1);
    f4acc(a0, *(const float4*)&h[(size_t)seg * F + j4]);  // self-loop
    float4 bv = *(const float4*)&b[j4];
    float  d  = dinv[seg];
    float4 o  = {bv.x + d * a0.x, bv.y + d * a0.y, bv.z + d * a0.z, bv.w + d * a0.w};
    *(float4*)&out[(size_t)seg * F + j4] = o;
}

extern "C" void kernel_launch(void* const* d_in, const int* in_sizes, int n_in,
                              void* d_out, int out_size, void* d_ws, size_t ws_size,
                              hipStream_t stream) {
    const float* x  = (const float*)d_in[0];
    const int*   ei = (const int*)d_in[1];
    const float* W1 = (const float*)d_in[2];
    const float* b1 = (const float*)d_in[3];
    const float* W2 = (const float*)d_in[4];
    const float* b2 = (const float*)d_in[5];
    const float* W3 = (const float*)d_in[6];
    const float* b3 = (const float*)d_in[7];
    const float* W4 = (const float*)d_in[8];
    const float* b4 = (const float*)d_in[9];

    const int N = in_sizes[0] / 128;  // 100000
    const int E = in_sizes[1] / 2;    // 1600000
    const int* row = ei;              // source
    const int* col = ei + E;          // destination
    const int n2 = N * NBKT;
    const int span = (N + NBKT - 1) / NBKT;  // 12500

    // ---- workspace layout (aliased to fit) ----------------------------------
    // persistent: offs2, dinv, eidx, X, H
    // transient:  cnt2 -> aliases X (scan reads cnt2 before agg1 writes X)
    //             cursor -> aliases H (scatter done before gemm1 writes H)
    //             bsum -> aliases eidx (scan done before scatter writes eidx)
    char* w = (char*)d_ws;
    int*   offs2 = (int*)w;                  w += (size_t)(n2 + 4) * 4;   // 16B-pad
    float* dinv  = (float*)w;                w += (size_t)N * 4;
    int*   eidx  = (int*)w;                  w += (size_t)E * 4;
    float* X     = (float*)w;                w += (size_t)N * 64 * 4;
    float* H     = (float*)w;
    int*   cnt2   = (int*)X;
    int*   cursor = (int*)H;
    int*   bsum   = eidx;
    float* out    = (float*)d_out;

    const int T   = 256;
    const int NB  = (N + T - 1) / T;   // 391
    const int NB2 = (n2 + T - 1) / T;  // 3125

    // ---- bucketed-CSR build + norm ------------------------------------------
    zero_i32_kernel<<<NB2, T, 0, stream>>>(cnt2, n2);
    hist2_kernel<<<(E + T - 1) / T, T, 0, stream>>>(row, col, cnt2, E, span);
    block_reduce_kernel<<<NB2, T, 0, stream>>>(cnt2, bsum, n2);
    scan_bsums_big_kernel<<<1, 512, 0, stream>>>(bsum, NB2);
    scan_kernel<<<NB2, T, 0, stream>>>(cnt2, bsum, offs2, n2);
    dinv2_kernel<<<NB, T, 0, stream>>>(offs2, dinv, N);
    copy_i32_kernel<<<NB2, T, 0, stream>>>(offs2, cursor, n2);
    scatter2_kernel<<<2048, T, 0, stream>>>(row, col, cursor, eidx, E, span);

    const int g64 = (N + 63) / 64;    // gemm blocks, 64 rows/block (F_OUT=64)
    const int g32 = (N + 127) / 128;  // gemm blocks, 128 rows/block (F_OUT=32)
    const int a64 = (N * 16 + T - 1) / T;  // agg blocks, 16 lanes/node
    const int a32 = (N * 8 + T - 1) / T;   // agg blocks, 8 lanes/node

    // ---- layer 1: x[128] -> 64 ---------------------------------------------
    gemm_tile_kernel<128, 64, false><<<g64, T, 0, stream>>>(x, W1, dinv, H, N);
    agg_csr_kernel<64><<<a64, T, 0, stream>>>(H, offs2, eidx, dinv, b1, X, N);
    // ---- layer 2 ------------------------------------------------------------
    gemm_tile_kernel<64, 64, true><<<g64, T, 0, stream>>>(X, W2, dinv, H, N);
    agg_csr_kernel<64><<<a64, T, 0, stream>>>(H, offs2, eidx, dinv, b2, X, N);
    // ---- layer 3 ------------------------------------------------------------
    gemm_tile_kernel<64, 64, true><<<g64, T, 0, stream>>>(X, W3, dinv, H, N);
    agg_csr_kernel<64><<<a64, T, 0, stream>>>(H, offs2, eidx, dinv, b3, X, N);
    // ---- layer 4: 64 -> 32, no ReLU, straight to d_out ----------------------
    gemm_tile_kernel<64, 32, true><<<g32, T, 0, stream>>>(X, W4, dinv, H, N);
    agg_csr_kernel<32><<<a32, T, 0, stream>>>(H, offs2, eidx, dinv, b4, out, N);
}

// Round 8
// 416.350 us; speedup vs baseline: 1.2885x; 1.2713x over previous
//
#include <hip/hip_runtime.h>
#include <hip/hip_fp16.h>

// ---------------------------------------------------------------------------
// GCN forward, source-bucketed-CSR, fp16 gather payload.
//   H (gemm output, pre-scaled by dinv[row]) is stored fp16: halves gather
//   bytes/requests/L2-lines in the agg (round-7: fetch floor reached at f32;
//   the limiter scales with payload). Accumulation and X/d_out stay f32.
// ---------------------------------------------------------------------------

#define NBKT 8

__global__ __launch_bounds__(256) void zero_i32_kernel(int* __restrict__ p, int n) {
    int i = blockIdx.x * blockDim.x + threadIdx.x;
    if (i < n) p[i] = 0;
}

// cnt2[c*8 + src/span] ++
__global__ __launch_bounds__(256) void hist2_kernel(const int* __restrict__ row,
                                                    const int* __restrict__ col,
                                                    int* __restrict__ cnt2, int E, int span) {
    int e = blockIdx.x * blockDim.x + threadIdx.x;
    if (e < E) {
        int c = col[e], r = row[e];
        atomicAdd(&cnt2[(size_t)c * NBKT + r / span], 1);
    }
}

__global__ __launch_bounds__(256) void dinv2_kernel(const int* __restrict__ offs2,
                                                    float* __restrict__ dinv, int N) {
    int i = blockIdx.x * blockDim.x + threadIdx.x;
    if (i < N) {
        int deg = offs2[i * NBKT + NBKT] - offs2[i * NBKT];
        dinv[i] = rsqrtf((float)deg + 1.0f);  // +1 self-loop
    }
}

__global__ __launch_bounds__(256) void block_reduce_kernel(const int* __restrict__ cnt,
                                                           int* __restrict__ bsum, int n) {
    __shared__ int s[256];
    int i = blockIdx.x * 256 + threadIdx.x;
    s[threadIdx.x] = (i < n) ? cnt[i] : 0;
    __syncthreads();
    for (int off = 128; off > 0; off >>= 1) {
        if (threadIdx.x < off) s[threadIdx.x] += s[threadIdx.x + off];
        __syncthreads();
    }
    if (threadIdx.x == 0) bsum[blockIdx.x] = s[0];
}

// single block, exclusive-scans bsum[nb] in place, any nb (chunks of 512)
__global__ __launch_bounds__(512) void scan_bsums_big_kernel(int* __restrict__ bsum, int nb) {
    __shared__ int s[512];
    int tid = threadIdx.x;
    int run = 0;
    for (int start = 0; start < nb; start += 512) {
        int i = start + tid;
        int v = (i < nb) ? bsum[i] : 0;
        s[tid] = v;
        __syncthreads();
        for (int off = 1; off < 512; off <<= 1) {
            int t = (tid >= off) ? s[tid - off] : 0;
            __syncthreads();
            s[tid] += t;
            __syncthreads();
        }
        if (i < nb) bsum[i] = s[tid] - v + run;  // exclusive + carry
        int tot = s[511];
        __syncthreads();
        run += tot;
    }
}

__global__ __launch_bounds__(256) void scan_kernel(const int* __restrict__ cnt,
                                                   const int* __restrict__ bsum,
                                                   int* __restrict__ offs, int n) {
    __shared__ int s[256];
    int i = blockIdx.x * 256 + threadIdx.x;
    int v = (i < n) ? cnt[i] : 0;
    s[threadIdx.x] = v;
    __syncthreads();
    for (int off = 1; off < 256; off <<= 1) {
        int t = (threadIdx.x >= off) ? s[threadIdx.x - off] : 0;
        __syncthreads();
        s[threadIdx.x] += t;
        __syncthreads();
    }
    int excl = s[threadIdx.x] - v + bsum[blockIdx.x];
    if (i < n) offs[i] = excl;
    if (i == n - 1) offs[n] = excl + v;
}

__global__ __launch_bounds__(256) void copy_i32_kernel(const int* __restrict__ src,
                                                       int* __restrict__ dst, int n) {
    int i = blockIdx.x * blockDim.x + threadIdx.x;
    if (i < n) dst[i] = src[i];
}

// XCD-partitioned by dest range (write locality on eidx/cursor); bucket slot
// chosen by source range.
__global__ __launch_bounds__(256) void scatter2_kernel(const int* __restrict__ row,
                                                       const int* __restrict__ col,
                                                       int* __restrict__ cursor,
                                                       int* __restrict__ eidx,
                                                       int E, int span) {
    const int part = blockIdx.x & 7;
    const int lo = part * span, hi = lo + span;
    const int nwg = gridDim.x >> 3;
    const int wg  = blockIdx.x >> 3;
    for (int e = wg * 256 + threadIdx.x; e < E; e += nwg * 256) {
        int c = col[e];
        if (c >= lo && c < hi) {
            int r = row[e];
            int pos = atomicAdd(&cursor[(size_t)c * NBKT + r / span], 1);
            eidx[pos] = r;
        }
    }
}

// H(fp16) = ((RELU? relu(in) : in) @ W) * dinv[row].  W is [F_IN,F_OUT] rowmaj.
// __launch_bounds__(256,4): cap VGPR at 128 (round-4: 248 VGPR / 9.6% occ was
// latency-bound). Inner unroll capped at 2 to avoid scratch spills.
template <int F_IN, int F_OUT, bool RELU>
__global__ __launch_bounds__(256, 4) void gemm_tile_kernel(const float* __restrict__ in,
                                                           const float* __restrict__ W,
                                                           const float* __restrict__ dinv,
                                                           ushort* __restrict__ outh, int N) {
    constexpr int TC   = F_OUT / 4;   // col-thread groups (16 or 8)
    constexpr int TR   = 256 / TC;    // row-thread groups (16 or 32)
    constexpr int ROWS = TR * 4;      // rows per block (64 or 128)
    constexpr int NKB  = F_IN / 64;   // k-blocks of 64
    __shared__ float sIn[ROWS][68];
    __shared__ float sW[64][F_OUT];

    const int tc = threadIdx.x % TC;
    const int tr = threadIdx.x / TC;
    const int r0 = blockIdx.x * ROWS;

    float acc[4][4] = {};

#pragma unroll
    for (int kb = 0; kb < NKB; ++kb) {
        if (kb) __syncthreads();
        for (int idx = threadIdx.x; idx < ROWS * 16; idx += 256) {
            int rr = idx / 16, c4 = (idx % 16) * 4;
            int gr = min(r0 + rr, N - 1);
            float4 v = *(const float4*)&in[(size_t)gr * F_IN + kb * 64 + c4];
            if (RELU) {
                v.x = fmaxf(v.x, 0.f); v.y = fmaxf(v.y, 0.f);
                v.z = fmaxf(v.z, 0.f); v.w = fmaxf(v.w, 0.f);
            }
            *(float4*)&sIn[rr][c4] = v;
        }
        for (int idx = threadIdx.x; idx < 64 * F_OUT / 4; idx += 256) {
            int kr = idx / (F_OUT / 4), c4 = (idx % (F_OUT / 4)) * 4;
            *(float4*)&sW[kr][c4] = *(const float4*)&W[(size_t)(kb * 64 + kr) * F_OUT + c4];
        }
        __syncthreads();
#pragma unroll 2
        for (int kk = 0; kk < 64; kk += 4) {
            float4 iv[4], wv[4];
#pragma unroll
            for (int i = 0; i < 4; ++i) iv[i] = *(const float4*)&sIn[tr * 4 + i][kk];
#pragma unroll
            for (int q = 0; q < 4; ++q) wv[q] = *(const float4*)&sW[kk + q][tc * 4];
#pragma unroll
            for (int i = 0; i < 4; ++i) {
                const float ik[4] = {iv[i].x, iv[i].y, iv[i].z, iv[i].w};
#pragma unroll
                for (int q = 0; q < 4; ++q) {
                    acc[i][0] = fmaf(ik[q], wv[q].x, acc[i][0]);
                    acc[i][1] = fmaf(ik[q], wv[q].y, acc[i][1]);
                    acc[i][2] = fmaf(ik[q], wv[q].z, acc[i][2]);
                    acc[i][3] = fmaf(ik[q], wv[q].w, acc[i][3]);
                }
            }
        }
    }
#pragma unroll
    for (int i = 0; i < 4; ++i) {
        int r = r0 + tr * 4 + i;
        if (r < N) {
            float d = dinv[r];
            ushort4 v;
            v.x = __half_as_ushort(__float2half(acc[i][0] * d));
            v.y = __half_as_ushort(__float2half(acc[i][1] * d));
            v.z = __half_as_ushort(__float2half(acc[i][2] * d));
            v.w = __half_as_ushort(__float2half(acc[i][3] * d));
            *(ushort4*)&outh[(size_t)r * F_OUT + tc * 4] = v;
        }
    }
}

__device__ inline void h8acc(float* acc, uint4 u) {
    const __half2* p = (const __half2*)&u;
#pragma unroll
    for (int i = 0; i < 4; ++i) {
        float2 f = __half22float2(p[i]);
        acc[2 * i]     += f.x;
        acc[2 * i + 1] += f.y;
    }
}

// out[c, jw*8..+7] = b + dinv[c]*( sum_{neighbors} H16[r] + H16[c] )
// F/8 lanes per destination node; each lane gathers 16 B = 8 fp16 features.
template <int F>
__global__ __launch_bounds__(256) void agg_half_kernel(const ushort* __restrict__ h,
                                                       const int* __restrict__ offs2,
                                                       const int* __restrict__ eidx,
                                                       const float* __restrict__ dinv,
                                                       const float* __restrict__ b,
                                                       float* __restrict__ out, int N) {
    constexpr int L = F / 8;  // lanes per node (8 or 4), also uint4s per row
    int tid = blockIdx.x * 256 + threadIdx.x;
    int seg = tid / L;
    int jw  = tid % L;
    if (seg >= N) return;
    const uint4* hv = (const uint4*)h;

    float a0[8] = {}, a1[8] = {};
    const int base = seg * NBKT;
    int ks = offs2[base];
#pragma unroll
    for (int q = 0; q < NBKT; ++q) {
        int ke = offs2[base + q + 1];
        int k = ks;
        for (; k + 2 <= ke; k += 2) {
            int r0 = eidx[k], r1 = eidx[k + 1];
            h8acc(a0, hv[(size_t)r0 * L + jw]);
            h8acc(a1, hv[(size_t)r1 * L + jw]);
        }
        if (k < ke) h8acc(a0, hv[(size_t)eidx[k] * L + jw]);
        ks = ke;
    }
    h8acc(a0, hv[(size_t)seg * L + jw]);  // self-loop
#pragma unroll
    for (int i = 0; i < 8; ++i) a0[i] += a1[i];

    float  d  = dinv[seg];
    float4 b0 = *(const float4*)&b[jw * 8];
    float4 b1 = *(const float4*)&b[jw * 8 + 4];
    float4 o0 = {b0.x + d * a0[0], b0.y + d * a0[1], b0.z + d * a0[2], b0.w + d * a0[3]};
    float4 o1 = {b1.x + d * a0[4], b1.y + d * a0[5], b1.z + d * a0[6], b1.w + d * a0[7]};
    *(float4*)&out[(size_t)seg * F + jw * 8]     = o0;
    *(float4*)&out[(size_t)seg * F + jw * 8 + 4] = o1;
}

extern "C" void kernel_launch(void* const* d_in, const int* in_sizes, int n_in,
                              void* d_out, int out_size, void* d_ws, size_t ws_size,
                              hipStream_t stream) {
    const float* x  = (const float*)d_in[0];
    const int*   ei = (const int*)d_in[1];
    const float* W1 = (const float*)d_in[2];
    const float* b1 = (const float*)d_in[3];
    const float* W2 = (const float*)d_in[4];
    const float* b2 = (const float*)d_in[5];
    const float* W3 = (const float*)d_in[6];
    const float* b3 = (const float*)d_in[7];
    const float* W4 = (const float*)d_in[8];
    const float* b4 = (const float*)d_in[9];

    const int N = in_sizes[0] / 128;  // 100000
    const int E = in_sizes[1] / 2;    // 1600000
    const int* row = ei;              // source
    const int* col = ei + E;          // destination
    const int n2 = N * NBKT;
    const int span = (N + NBKT - 1) / NBKT;  // 12500

    // ---- workspace layout (aliased to fit) ----------------------------------
    // persistent: offs2, dinv, eidx, X(f32), H(fp16)
    // transient:  cnt2 -> aliases X; cursor -> aliases H area (as int, H is
    //             12.8MB but cursor needs 3.2MB, fits); bsum -> aliases eidx
    char* w = (char*)d_ws;
    int*    offs2 = (int*)w;                 w += (size_t)(n2 + 4) * 4;   // 16B-pad
    float*  dinv  = (float*)w;               w += (size_t)N * 4;
    int*    eidx  = (int*)w;                 w += (size_t)E * 4;
    float*  X     = (float*)w;               w += (size_t)N * 64 * 4;
    ushort* H     = (ushort*)w;              // N*64 fp16 = 12.8 MB
    int*    cnt2   = (int*)X;
    int*    cursor = (int*)H;
    int*    bsum   = eidx;
    float*  out    = (float*)d_out;

    const int T   = 256;
    const int NB  = (N + T - 1) / T;   // 391
    const int NB2 = (n2 + T - 1) / T;  // 3125

    // ---- bucketed-CSR build + norm ------------------------------------------
    zero_i32_kernel<<<NB2, T, 0, stream>>>(cnt2, n2);
    hist2_kernel<<<(E + T - 1) / T, T, 0, stream>>>(row, col, cnt2, E, span);
    block_reduce_kernel<<<NB2, T, 0, stream>>>(cnt2, bsum, n2);
    scan_bsums_big_kernel<<<1, 512, 0, stream>>>(bsum, NB2);
    scan_kernel<<<NB2, T, 0, stream>>>(cnt2, bsum, offs2, n2);
    dinv2_kernel<<<NB, T, 0, stream>>>(offs2, dinv, N);
    copy_i32_kernel<<<NB2, T, 0, stream>>>(offs2, cursor, n2);
    scatter2_kernel<<<2048, T, 0, stream>>>(row, col, cursor, eidx, E, span);

    const int g64 = (N + 63) / 64;    // gemm blocks, 64 rows/block (F_OUT=64)
    const int g32 = (N + 127) / 128;  // gemm blocks, 128 rows/block (F_OUT=32)
    const int a64 = (N * 8 + T - 1) / T;   // agg blocks, 8 lanes/node
    const int a32 = (N * 4 + T - 1) / T;   // agg blocks, 4 lanes/node

    // ---- layer 1: x[128] -> 64 ---------------------------------------------
    gemm_tile_kernel<128, 64, false><<<g64, T, 0, stream>>>(x, W1, dinv, H, N);
    agg_half_kernel<64><<<a64, T, 0, stream>>>(H, offs2, eidx, dinv, b1, X, N);
    // ---- layer 2 ------------------------------------------------------------
    gemm_tile_kernel<64, 64, true><<<g64, T, 0, stream>>>(X, W2, dinv, H, N);
    agg_half_kernel<64><<<a64, T, 0, stream>>>(H, offs2, eidx, dinv, b2, X, N);
    // ---- layer 3 ------------------------------------------------------------
    gemm_tile_kernel<64, 64, true><<<g64, T, 0, stream>>>(X, W3, dinv, H, N);
    agg_half_kernel<64><<<a64, T, 0, stream>>>(H, offs2, eidx, dinv, b3, X, N);
    // ---- layer 4: 64 -> 32, no ReLU, straight to d_out ----------------------
    gemm_tile_kernel<64, 32, true><<<g32, T, 0, stream>>>(X, W4, dinv, H, N);
    agg_half_kernel<32><<<a32, T, 0, stream>>>(H, offs2, eidx, dinv, b4, out, N);
}